// Round 5
// baseline (272.018 us; speedup 1.0000x reference)
//
#include <hip/hip_runtime.h>

#define Bn 64
#define Tn 512
#define Hn 768
#define Ln 21
#define EM_ELEMS (Bn*Tn*Ln)

// tiny ws layout (floats)
#define LZ_OFF   64
#define TAG_OFF  128
#define DIFF_OFF 192
#define NVB 22   // ceil(64 batches / 3 per wave)

__device__ __forceinline__ float rl(float x, int i){
    return __int_as_float(__builtin_amdgcn_readlane(__float_as_int(x), i));
}
__device__ __forceinline__ float bperm(int addr, float x){
    return __int_as_float(__builtin_amdgcn_ds_bpermute(addr, __float_as_int(x)));
}

// ---------------- emissions = hidden @ W + b  (split-K x4, LDS combine) ----------------
__global__ __launch_bounds__(256) void emis_kernel(
    const float* __restrict__ hidden, const float* __restrict__ W,
    const float* __restrict__ bias, float* __restrict__ em)
{
    __shared__ float part[4][64][22];
    const int lane = threadIdx.x & 63;
    const int w    = threadIdx.x >> 6;
    const int row  = blockIdx.x*64 + lane;
    const int wb   = 64 + (lane < 20 ? lane : 19);
    const float4* h4 = (const float4*)(hidden + (size_t)row*Hn) + w*48;
    const float*  Wp = W + w*(192*Ln);
    float acc[Ln];
    #pragma unroll
    for (int j=0;j<Ln;++j) acc[j]=0.f;
    float4 hcur = h4[0];
    float Wa = Wp[lane], Wb2 = Wp[wb];
    for (int t=0;t<48;++t){
        float4 hn = hcur; float Wan = Wa, Wbn = Wb2;
        if (t<47){ hn = h4[t+1]; Wan = Wp[(t+1)*84+lane]; Wbn = Wp[(t+1)*84+wb]; }
        const float* hv = &hcur.x;
        #pragma unroll
        for (int c=0;c<4;++c){
            float x = hv[c];
            #pragma unroll
            for (int j=0;j<Ln;++j){
                const int idx = c*Ln+j;
                float wv = (idx<64) ? rl(Wa, idx) : rl(Wb2, idx-64);
                acc[j] = fmaf(x, wv, acc[j]);
            }
        }
        hcur=hn; Wa=Wan; Wb2=Wbn;
    }
    #pragma unroll
    for (int j=0;j<Ln;++j) part[w][lane][j] = acc[j];
    __syncthreads();
    float* ob = em + (size_t)blockIdx.x*64*Ln;
    for (int e=threadIdx.x; e<64*Ln; e+=256){
        int r = e/Ln, j = e-r*Ln;
        ob[e] = ((part[0][r][j]+part[1][r][j])+(part[2][r][j]+part[3][r][j])) + bias[j];
    }
}

// ---------------- scans: 3 chains per wave. blocks 0..21 viterbi, 22..43 NLL ----------------
__global__ __launch_bounds__(64) void scan_kernel(
    const float* __restrict__ em, const int* __restrict__ labels,
    const int* __restrict__ amask, const float* __restrict__ st,
    const float* __restrict__ et, const float* __restrict__ trans,
    float* __restrict__ ws, float* __restrict__ alf)
{
    __shared__ float red_s[64];
    const int lane = threadIdx.x;
    const int g    = (lane < 21) ? 0 : (lane < 42) ? 1 : 2;
    const int j0   = lane - g*21;                 // 0..20 (lane63 -> 21)
    const bool act = (j0 < 21) && (lane < 63);
    const int  j   = act ? j0 : 0;
    const int  g21 = g*21;
    const int  mode = (blockIdx.x < NVB) ? 0 : 1;
    const int  vb   = mode ? (blockIdx.x - NVB) : blockIdx.x;
    int batch = vb*3 + g;
    const bool real = (batch < Bn) && act;
    if (batch >= Bn) batch = Bn-1;
    const float* emb = em + (size_t)batch*Tn*Ln;

    int va[Ln];                                   // bpermute byte addrs, loop-invariant
    #pragma unroll
    for (int i=0;i<Ln;++i) va[i] = (g21 + i) << 2;

    if (mode == 0){
        // ---- Viterbi forward: value recurrence; alpha streamed into logits region ----
        float trc[Ln];
        #pragma unroll
        for (int i=0;i<Ln;++i) trc[i] = trans[i*Ln + j];
        const int* mk = amask + batch*Tn;
        float sc = st[j] + emb[j];
        float* sp = alf + (size_t)batch*Tn*Ln + j;
        if (real) *sp = sc;
        sp += Ln;
        float e1 = emb[Ln + j];    int m1 = mk[1];
        float e2 = emb[2*Ln + j];  int m2 = mk[2];
        for (int t=1;t<Tn;++t){
            float ec = e1; int mc = m1;
            e1 = e2; m1 = m2;
            int tn = (t+2 < Tn) ? (t+2) : (Tn-1);
            e2 = emb[tn*Ln + j]; m2 = mk[tn];
            float v[Ln];
            #pragma unroll
            for (int i=0;i<Ln;++i) v[i] = bperm(va[i], sc) + trc[i];
            float a0 = fmaxf(fmaxf(v[0],v[1]),v[2]);
            float a1 = fmaxf(fmaxf(v[3],v[4]),v[5]);
            float a2 = fmaxf(fmaxf(v[6],v[7]),v[8]);
            float a3 = fmaxf(fmaxf(v[9],v[10]),v[11]);
            float a4 = fmaxf(fmaxf(v[12],v[13]),v[14]);
            float a5 = fmaxf(fmaxf(v[15],v[16]),v[17]);
            float a6 = fmaxf(fmaxf(v[18],v[19]),v[20]);
            float b0 = fmaxf(fmaxf(a0,a1),a2);
            float b1 = fmaxf(fmaxf(a3,a4),a5);
            float best = fmaxf(fmaxf(b0,b1),a6);
            float scn = best + ec;
            sc = mc ? scn : sc;
            if (real) *sp = sc;
            sp += Ln;
        }
        // per-group first-max argmax via LDS (off critical path)
        red_s[lane] = act ? (sc + et[j]) : -1e30f;
        __syncthreads();
        float vv[Ln]; float best = -1e31f;
        #pragma unroll
        for (int i=0;i<Ln;++i){ vv[i] = red_s[g21+i]; best = fmaxf(best, vv[i]); }
        unsigned bm = 0u;
        #pragma unroll
        for (int i=0;i<Ln;++i) bm |= (vv[i]==best) ? (1u<<i) : 0u;
        int idx = __ffs(bm) - 1;
        if (real && j0==0) ((int*)(ws+TAG_OFF))[batch] = idx;
    } else {
        // ---- NLL forward in scaled-prob domain ----
        float Ec[Ln];
        #pragma unroll
        for (int i=0;i<Ln;++i) Ec[i] = __expf(trans[i*Ln + j]);
        const int* lb = labels + batch*Tn;
        float p = act ? __expf(st[j] + emb[j]) : 0.f;
        float M = 0.f;
        float e1 = emb[Ln + j];    int l1 = lb[1];
        float e2 = emb[2*Ln + j];  int l2 = lb[2];
        for (int t=1;t<Tn;++t){
            float ec = e1; int lc = l1;
            e1 = e2; l1 = l2;
            int tn = (t+2 < Tn) ? (t+2) : (Tn-1);
            e2 = emb[tn*Ln + j]; l2 = lb[tn];
            float pe = __expf(ec);
            float s0=0.f,s1=0.f,s2=0.f;
            #pragma unroll
            for (int i=0;i<Ln;++i){
                float pi = bperm(va[i], p);
                if      (i%3==0) s0 = fmaf(pi, Ec[i], s0);
                else if (i%3==1) s1 = fmaf(pi, Ec[i], s1);
                else             s2 = fmaf(pi, Ec[i], s2);
            }
            float pn = ((s0+s1)+s2) * pe;
            p = (lc != -100) ? pn : p;
            if ((t & 7) == 0){
                float p0 = bperm(va[0], p);
                int e; frexpf(p0, &e);
                p = ldexpf(p, -e);
                M += (float)e * 0.6931471805599453f;
            }
        }
        red_s[lane] = act ? (p * __expf(et[j])) : 0.f;
        __syncthreads();
        float val = 0.f;
        #pragma unroll
        for (int i=0;i<Ln;++i) val += red_s[g21+i];
        if (real && j0==0) (ws+LZ_OFF)[batch] = M + __logf(val);
    }
}

// ---------------- post: blocks 0..63 bp-recompute+backtrack+logits; 64..127 gold score ----------------
__global__ __launch_bounds__(512) void post_kernel(
    const float* __restrict__ em, const int* __restrict__ labels,
    const int* __restrict__ amask, const float* __restrict__ st,
    const float* __restrict__ et, const float* __restrict__ trans,
    float* __restrict__ ws, float* __restrict__ logits)
{
    const int b    = blockIdx.x & (Bn-1);
    const int mode = blockIdx.x >> 6;
    const int tid  = threadIdx.x;

    if (mode == 0){
        __shared__ unsigned char hist_s[Tn*Ln];
        __shared__ int lab_s[Tn];
        __shared__ int path_s[Tn];
        __shared__ unsigned char comp_s[64*Ln];
        __shared__ unsigned char ent_s[64];
        lab_s[tid] = amask[b*Tn + tid];
        const int w = tid >> 6, lane = tid & 63;
        const bool act = lane < Ln;
        const int jc = act ? lane : 0;
        float trc[Ln];
        #pragma unroll
        for (int i=0;i<Ln;++i) trc[i] = trans[i*Ln + jc];
        __syncthreads();
        const float* alf = logits + (size_t)b*Tn*Ln;   // alpha lives here (from scan)
        for (int t = 1+w; t < Tn; t += 8){
            const float* ar = alf + (size_t)(t-1)*Ln;
            float a[Ln];
            #pragma unroll
            for (int i=0;i<Ln;++i) a[i] = ar[i];
            int bp = lane;
            if (lab_s[t]){
                float v[Ln];
                #pragma unroll
                for (int i=0;i<Ln;++i) v[i] = a[i] + trc[i];
                float a0 = fmaxf(fmaxf(v[0],v[1]),v[2]);
                float a1 = fmaxf(fmaxf(v[3],v[4]),v[5]);
                float a2 = fmaxf(fmaxf(v[6],v[7]),v[8]);
                float a3 = fmaxf(fmaxf(v[9],v[10]),v[11]);
                float a4 = fmaxf(fmaxf(v[12],v[13]),v[14]);
                float a5 = fmaxf(fmaxf(v[15],v[16]),v[17]);
                float a6 = fmaxf(fmaxf(v[18],v[19]),v[20]);
                float b0 = fmaxf(fmaxf(a0,a1),a2);
                float b1 = fmaxf(fmaxf(a3,a4),a5);
                float best = fmaxf(fmaxf(b0,b1),a6);
                unsigned bm = 0u;
                #pragma unroll
                for (int i=0;i<Ln;++i) bm |= (v[i]==best) ? (1u<<i) : 0u;
                bp = __ffs(bm) - 1;
            }
            if (act) hist_s[t*Ln + lane] = (unsigned char)bp;
        }
        __syncthreads();
        if (tid < 64){
            unsigned char cur[Ln];
            #pragma unroll
            for (int q=0;q<Ln;++q) cur[q] = (unsigned char)q;
            #pragma unroll
            for (int k=8;k>=1;--k){
                int ta = 8*tid + k;
                if (ta < Tn){
                    const unsigned char* hr = &hist_s[ta*Ln];
                    #pragma unroll
                    for (int q=0;q<Ln;++q) cur[q] = hr[cur[q]];
                }
            }
            #pragma unroll
            for (int q=0;q<Ln;++q) comp_s[tid*Ln+q] = cur[q];
        }
        __syncthreads();
        if (tid==0){
            int cg = ((const int*)(ws+TAG_OFF))[b];
            for (int l=63;l>=0;--l){ ent_s[l]=(unsigned char)cg; cg = comp_s[l*Ln+cg]; }
        }
        __syncthreads();
        if (tid < 64){
            int s = ent_s[tid];
            if (tid==63) path_s[Tn-1] = s;
            #pragma unroll
            for (int k=8;k>=1;--k){
                int ta = 8*tid + k;
                if (ta < Tn){ s = hist_s[ta*Ln+s]; path_s[ta-1] = s; }
            }
        }
        __syncthreads();   // all alpha reads done; overwrite with one-hot
        float* lg = logits + (size_t)b*Tn*Ln;
        for (int id2=tid; id2<Tn*Ln; id2+=512){
            int t = id2/Ln; int jj = id2 - t*Ln;
            lg[id2] = (lab_s[t] && path_s[t]==jj) ? 1.0f : 0.0f;
        }
    } else {
        __shared__ float red_s[8];
        __shared__ int  redc_s[8];
        const int* lb = labels + b*Tn;
        int labt = lb[tid];
        float term = 0.f;
        int c = (tid==0 || labt != -100) ? 1 : 0;
        if (tid>=1 && labt != -100){
            int lp = lb[tid-1]; if (lp<0) lp=0;
            term = trans[lp*Ln+labt] + em[((size_t)b*Tn+tid)*Ln + labt];
        }
        #pragma unroll
        for (int off=32; off>=1; off>>=1){
            term += __shfl_xor(term, off, 64);
            c    += __shfl_xor(c,    off, 64);
        }
        int w = tid>>6;
        if ((tid&63)==0){ red_s[w]=term; redc_s[w]=c; }
        __syncthreads();
        if (tid==0){
            float sum=0.f; int cnt=0;
            #pragma unroll
            for (int q=0;q<8;++q){ sum+=red_s[q]; cnt+=redc_s[q]; }
            int l0 = lb[0]; int tag0 = l0<0?0:l0;
            float score = st[tag0] + em[(size_t)b*Tn*Ln + tag0] + sum;
            int li = cnt-1; int ll = lb[li]; int lt = ll<0?0:ll;
            score += et[lt];
            (ws+DIFF_OFF)[b] = score - (ws+LZ_OFF)[b];
        }
    }
}

// ---------------- finalize: nll = -mean(score - logZ) ----------------
__global__ __launch_bounds__(64) void fin_kernel(const float* __restrict__ ws,
                                                 float* __restrict__ out0)
{
    float v = (ws+DIFF_OFF)[threadIdx.x];
    #pragma unroll
    for (int off=32; off>=1; off>>=1) v += __shfl_xor(v, off, 64);
    if (threadIdx.x==0) out0[0] = -(v * (1.0f/64.0f));
}

extern "C" void kernel_launch(void* const* d_in, const int* in_sizes, int n_in,
                              void* d_out, int out_size, void* d_ws, size_t ws_size,
                              hipStream_t stream)
{
    (void)in_sizes; (void)n_in; (void)out_size; (void)ws_size;
    const float* hidden = (const float*)d_in[0];
    const float* W      = (const float*)d_in[1];
    const float* bias   = (const float*)d_in[2];
    const float* st     = (const float*)d_in[3];
    const float* et     = (const float*)d_in[4];
    const float* trans  = (const float*)d_in[5];
    const int*   labels = (const int*)d_in[6];
    const int*   amask  = (const int*)d_in[7];

    float* out    = (float*)d_out;
    float* nll    = out;
    float* logits = out + 1;
    float* em     = out + 1 + EM_ELEMS;
    float* ws     = (float*)d_ws;

    emis_kernel<<<dim3(Bn*Tn/64), dim3(256), 0, stream>>>(hidden, W, bias, em);
    scan_kernel<<<dim3(2*NVB), dim3(64), 0, stream>>>(em, labels, amask, st, et, trans, ws, logits);
    post_kernel<<<dim3(2*Bn), dim3(512), 0, stream>>>(em, labels, amask, st, et, trans, ws, logits);
    fin_kernel<<<dim3(1), dim3(64), 0, stream>>>(ws, nll);
}

// Round 6
// 204.428 us; speedup vs baseline: 1.3306x; 1.3306x over previous
//
#include <hip/hip_runtime.h>

#define Bn 64
#define Tn 512
#define Hn 768
#define Ln 21
#define EM_ELEMS (Bn*Tn*Ln)

// tiny ws layout (floats)
#define LZ_OFF   64
#define TAG_OFF  128
#define DIFF_OFF 192

__device__ __forceinline__ float rl(float x, int i){
    return __int_as_float(__builtin_amdgcn_readlane(__float_as_int(x), i));
}

// ---------------- emissions = hidden @ W + b  (split-K x4, LDS combine) ----------------
__global__ __launch_bounds__(256) void emis_kernel(
    const float* __restrict__ hidden, const float* __restrict__ W,
    const float* __restrict__ bias, float* __restrict__ em)
{
    __shared__ float part[4][64][22];
    const int lane = threadIdx.x & 63;
    const int w    = threadIdx.x >> 6;
    const int row  = blockIdx.x*64 + lane;
    const int wb   = 64 + (lane < 20 ? lane : 19);
    const float4* h4 = (const float4*)(hidden + (size_t)row*Hn) + w*48;
    const float*  Wp = W + w*(192*Ln);
    float acc[Ln];
    #pragma unroll
    for (int j=0;j<Ln;++j) acc[j]=0.f;
    float4 hcur = h4[0];
    float Wa = Wp[lane], Wb2 = Wp[wb];
    for (int t=0;t<48;++t){
        float4 hn = hcur; float Wan = Wa, Wbn = Wb2;
        if (t<47){ hn = h4[t+1]; Wan = Wp[(t+1)*84+lane]; Wbn = Wp[(t+1)*84+wb]; }
        const float* hv = &hcur.x;
        #pragma unroll
        for (int c=0;c<4;++c){
            float x = hv[c];
            #pragma unroll
            for (int j=0;j<Ln;++j){
                const int idx = c*Ln+j;
                float wv = (idx<64) ? rl(Wa, idx) : rl(Wb2, idx-64);
                acc[j] = fmaf(x, wv, acc[j]);
            }
        }
        hcur=hn; Wa=Wan; Wb2=Wbn;
    }
    #pragma unroll
    for (int j=0;j<Ln;++j) part[w][lane][j] = acc[j];
    __syncthreads();
    float* ob = em + (size_t)blockIdx.x*64*Ln;
    for (int e=threadIdx.x; e<64*Ln; e+=256){
        int r = e/Ln, j = e-r*Ln;
        ob[e] = ((part[0][r][j]+part[1][r][j])+(part[2][r][j]+part[3][r][j])) + bias[j];
    }
}

// ---------------- scan: 1 block per batch; wave0 = viterbi, wave1 = NLL; em in LDS ----------------
__global__ __launch_bounds__(128) void scan_kernel(
    const float* __restrict__ em, const int* __restrict__ labels,
    const int* __restrict__ amask, const float* __restrict__ st,
    const float* __restrict__ et, const float* __restrict__ trans,
    float* __restrict__ ws, float* __restrict__ alf)
{
    __shared__ float em_s[Tn*Ln];   // 43008 B
    __shared__ int   mk_s[Tn];      // 2048 B
    __shared__ int   lb_s[Tn];      // 2048 B

    const int b    = blockIdx.x;
    const int tid  = threadIdx.x;
    const int wv   = tid >> 6;
    const int lane = tid & 63;
    const float* emb = em + (size_t)b*Tn*Ln;

    for (int i=tid; i<Tn*Ln; i+=128) em_s[i] = emb[i];
    for (int t=tid; t<Tn; t+=128){ mk_s[t] = amask[b*Tn+t]; lb_s[t] = labels[b*Tn+t]; }
    __syncthreads();

    const bool act = (lane < Ln);
    const int  j   = act ? lane : 0;

    if (wv == 0){
        // ---- Viterbi forward: value recurrence; alpha streamed into logits region ----
        float trc[Ln];
        #pragma unroll
        for (int i=0;i<Ln;++i) trc[i] = trans[i*Ln + j];
        float sc = st[j] + em_s[j];
        float* sp = alf + (size_t)b*Tn*Ln + j;
        if (act) *sp = sc;
        sp += Ln;
        float e1 = em_s[Ln + j];    int m1 = mk_s[1];
        float e2 = em_s[2*Ln + j];  int m2 = mk_s[2];
        for (int t=1;t<Tn;++t){
            float ec = e1; int mc = m1;
            e1 = e2; m1 = m2;
            int tn = (t+2 < Tn) ? (t+2) : (Tn-1);
            e2 = em_s[tn*Ln + j]; m2 = mk_s[tn];
            float v[Ln];
            #pragma unroll
            for (int i=0;i<Ln;++i) v[i] = rl(sc,i) + trc[i];
            float a0 = fmaxf(fmaxf(v[0],v[1]),v[2]);
            float a1 = fmaxf(fmaxf(v[3],v[4]),v[5]);
            float a2 = fmaxf(fmaxf(v[6],v[7]),v[8]);
            float a3 = fmaxf(fmaxf(v[9],v[10]),v[11]);
            float a4 = fmaxf(fmaxf(v[12],v[13]),v[14]);
            float a5 = fmaxf(fmaxf(v[15],v[16]),v[17]);
            float a6 = fmaxf(fmaxf(v[18],v[19]),v[20]);
            float b0 = fmaxf(fmaxf(a0,a1),a2);
            float b1 = fmaxf(fmaxf(a3,a4),a5);
            float best = fmaxf(fmaxf(b0,b1),a6);
            float scn = best + ec;
            sc = mc ? scn : sc;
            if (act) *sp = sc;
            sp += Ln;
        }
        float val = act ? (sc + et[j]) : -1e30f;
        int   idx = act ? j : 1000;
        #pragma unroll
        for (int off=32; off>=1; off>>=1){
            float ov = __shfl_xor(val, off, 64);
            int   oi = __shfl_xor(idx, off, 64);
            if (ov > val || (ov==val && oi<idx)){ val=ov; idx=oi; }
        }
        if (lane==0) ((int*)(ws+TAG_OFF))[b] = idx;
    } else {
        // ---- NLL forward in scaled-prob domain ----
        float Ec[Ln];
        #pragma unroll
        for (int i=0;i<Ln;++i) Ec[i] = __expf(trans[i*Ln + j]);
        float p = act ? __expf(st[j] + em_s[j]) : 0.f;
        float M = 0.f;
        float e1 = em_s[Ln + j];    int l1 = lb_s[1];
        float e2 = em_s[2*Ln + j];  int l2 = lb_s[2];
        for (int t=1;t<Tn;++t){
            float ec = e1; int lc = l1;
            e1 = e2; l1 = l2;
            int tn = (t+2 < Tn) ? (t+2) : (Tn-1);
            e2 = em_s[tn*Ln + j]; l2 = lb_s[tn];
            float pe = __expf(ec);
            float s0=0.f,s1=0.f,s2=0.f;
            #pragma unroll
            for (int i=0;i<Ln;++i){
                float pi = rl(p,i);
                if      (i%3==0) s0 = fmaf(pi, Ec[i], s0);
                else if (i%3==1) s1 = fmaf(pi, Ec[i], s1);
                else             s2 = fmaf(pi, Ec[i], s2);
            }
            float pn = ((s0+s1)+s2) * pe;
            p = (lc != -100) ? pn : p;
            if ((t & 7) == 0){
                float p0 = rl(p,0);
                int e; frexpf(p0, &e);
                p = ldexpf(p, -e);
                M += (float)e * 0.6931471805599453f;
            }
        }
        float val = act ? (p * __expf(et[j])) : 0.f;
        #pragma unroll
        for (int off=32; off>=1; off>>=1) val += __shfl_xor(val, off, 64);
        if (lane==0) (ws+LZ_OFF)[b] = M + __logf(val);
    }
}

// ---------------- post: blocks 0..63 bp-recompute+backtrack+logits; 64..127 gold score ----------------
__global__ __launch_bounds__(512) void post_kernel(
    const float* __restrict__ em, const int* __restrict__ labels,
    const int* __restrict__ amask, const float* __restrict__ st,
    const float* __restrict__ et, const float* __restrict__ trans,
    float* __restrict__ ws, float* __restrict__ logits)
{
    const int b    = blockIdx.x & (Bn-1);
    const int mode = blockIdx.x >> 6;
    const int tid  = threadIdx.x;

    if (mode == 0){
        __shared__ unsigned char hist_s[Tn*Ln];
        __shared__ int lab_s[Tn];
        __shared__ int path_s[Tn];
        __shared__ unsigned char comp_s[64*Ln];
        __shared__ unsigned char ent_s[64];
        lab_s[tid] = amask[b*Tn + tid];
        const int w = tid >> 6, lane = tid & 63;
        const bool act = lane < Ln;
        const int jc = act ? lane : 0;
        float trc[Ln];
        #pragma unroll
        for (int i=0;i<Ln;++i) trc[i] = trans[i*Ln + jc];
        __syncthreads();
        const float* alf = logits + (size_t)b*Tn*Ln;   // alpha lives here (from scan)
        for (int t = 1+w; t < Tn; t += 8){
            const float* ar = alf + (size_t)(t-1)*Ln;
            float a[Ln];
            #pragma unroll
            for (int i=0;i<Ln;++i) a[i] = ar[i];
            int bp = lane;
            if (lab_s[t]){
                float v[Ln];
                #pragma unroll
                for (int i=0;i<Ln;++i) v[i] = a[i] + trc[i];
                float a0 = fmaxf(fmaxf(v[0],v[1]),v[2]);
                float a1 = fmaxf(fmaxf(v[3],v[4]),v[5]);
                float a2 = fmaxf(fmaxf(v[6],v[7]),v[8]);
                float a3 = fmaxf(fmaxf(v[9],v[10]),v[11]);
                float a4 = fmaxf(fmaxf(v[12],v[13]),v[14]);
                float a5 = fmaxf(fmaxf(v[15],v[16]),v[17]);
                float a6 = fmaxf(fmaxf(v[18],v[19]),v[20]);
                float b0 = fmaxf(fmaxf(a0,a1),a2);
                float b1 = fmaxf(fmaxf(a3,a4),a5);
                float best = fmaxf(fmaxf(b0,b1),a6);
                unsigned bm = 0u;
                #pragma unroll
                for (int i=0;i<Ln;++i) bm |= (v[i]==best) ? (1u<<i) : 0u;
                bp = __ffs(bm) - 1;
            }
            if (act) hist_s[t*Ln + lane] = (unsigned char)bp;
        }
        __syncthreads();
        if (tid < 64){
            unsigned char cur[Ln];
            #pragma unroll
            for (int q=0;q<Ln;++q) cur[q] = (unsigned char)q;
            #pragma unroll
            for (int k=8;k>=1;--k){
                int ta = 8*tid + k;
                if (ta < Tn){
                    const unsigned char* hr = &hist_s[ta*Ln];
                    #pragma unroll
                    for (int q=0;q<Ln;++q) cur[q] = hr[cur[q]];
                }
            }
            #pragma unroll
            for (int q=0;q<Ln;++q) comp_s[tid*Ln+q] = cur[q];
        }
        __syncthreads();
        if (tid==0){
            int cg = ((const int*)(ws+TAG_OFF))[b];
            for (int l=63;l>=0;--l){ ent_s[l]=(unsigned char)cg; cg = comp_s[l*Ln+cg]; }
        }
        __syncthreads();
        if (tid < 64){
            int s = ent_s[tid];
            if (tid==63) path_s[Tn-1] = s;
            #pragma unroll
            for (int k=8;k>=1;--k){
                int ta = 8*tid + k;
                if (ta < Tn){ s = hist_s[ta*Ln+s]; path_s[ta-1] = s; }
            }
        }
        __syncthreads();   // all alpha reads done; overwrite with one-hot
        float* lg = logits + (size_t)b*Tn*Ln;
        for (int id2=tid; id2<Tn*Ln; id2+=512){
            int t = id2/Ln; int jj = id2 - t*Ln;
            lg[id2] = (lab_s[t] && path_s[t]==jj) ? 1.0f : 0.0f;
        }
    } else {
        __shared__ float red_s[8];
        __shared__ int  redc_s[8];
        const int* lb = labels + b*Tn;
        int labt = lb[tid];
        float term = 0.f;
        int c = (tid==0 || labt != -100) ? 1 : 0;
        if (tid>=1 && labt != -100){
            int lp = lb[tid-1]; if (lp<0) lp=0;
            term = trans[lp*Ln+labt] + em[((size_t)b*Tn+tid)*Ln + labt];
        }
        #pragma unroll
        for (int off=32; off>=1; off>>=1){
            term += __shfl_xor(term, off, 64);
            c    += __shfl_xor(c,    off, 64);
        }
        int w = tid>>6;
        if ((tid&63)==0){ red_s[w]=term; redc_s[w]=c; }
        __syncthreads();
        if (tid==0){
            float sum=0.f; int cnt=0;
            #pragma unroll
            for (int q=0;q<8;++q){ sum+=red_s[q]; cnt+=redc_s[q]; }
            int l0 = lb[0]; int tag0 = l0<0?0:l0;
            float score = st[tag0] + em[(size_t)b*Tn*Ln + tag0] + sum;
            int li = cnt-1; int ll = lb[li]; int lt = ll<0?0:ll;
            score += et[lt];
            (ws+DIFF_OFF)[b] = score - (ws+LZ_OFF)[b];
        }
    }
}

// ---------------- finalize: nll = -mean(score - logZ) ----------------
__global__ __launch_bounds__(64) void fin_kernel(const float* __restrict__ ws,
                                                 float* __restrict__ out0)
{
    float v = (ws+DIFF_OFF)[threadIdx.x];
    #pragma unroll
    for (int off=32; off>=1; off>>=1) v += __shfl_xor(v, off, 64);
    if (threadIdx.x==0) out0[0] = -(v * (1.0f/64.0f));
}

extern "C" void kernel_launch(void* const* d_in, const int* in_sizes, int n_in,
                              void* d_out, int out_size, void* d_ws, size_t ws_size,
                              hipStream_t stream)
{
    (void)in_sizes; (void)n_in; (void)out_size; (void)ws_size;
    const float* hidden = (const float*)d_in[0];
    const float* W      = (const float*)d_in[1];
    const float* bias   = (const float*)d_in[2];
    const float* st     = (const float*)d_in[3];
    const float* et     = (const float*)d_in[4];
    const float* trans  = (const float*)d_in[5];
    const int*   labels = (const int*)d_in[6];
    const int*   amask  = (const int*)d_in[7];

    float* out    = (float*)d_out;
    float* nll    = out;
    float* logits = out + 1;
    float* em     = out + 1 + EM_ELEMS;
    float* ws     = (float*)d_ws;

    emis_kernel<<<dim3(Bn*Tn/64), dim3(256), 0, stream>>>(hidden, W, bias, em);
    scan_kernel<<<dim3(Bn), dim3(128), 0, stream>>>(em, labels, amask, st, et, trans, ws, logits);
    post_kernel<<<dim3(2*Bn), dim3(512), 0, stream>>>(em, labels, amask, st, et, trans, ws, logits);
    fin_kernel<<<dim3(1), dim3(64), 0, stream>>>(ws, nll);
}

// Round 7
// 163.392 us; speedup vs baseline: 1.6648x; 1.2512x over previous
//
#include <hip/hip_runtime.h>

#define Bn 64
#define Tn 512
#define Hn 768
#define Ln 21
#define EM_ELEMS (Bn*Tn*Ln)

// tiny ws layout (floats)
#define DUMP_OFF 0
#define LZ_OFF   64
#define TAG_OFF  128
#define DIFF_OFF 192

__device__ __forceinline__ float rl(float x, int i){
    return __int_as_float(__builtin_amdgcn_readlane(__float_as_int(x), i));
}

// 21 readlanes into 21 DISTINCT SGPRs in one asm block (pipelined, no SGPR reuse hazard)
#define READLANES(src, A) \
    asm volatile( \
        "v_readlane_b32 %0, %[v], 0\n\t" \
        "v_readlane_b32 %1, %[v], 1\n\t" \
        "v_readlane_b32 %2, %[v], 2\n\t" \
        "v_readlane_b32 %3, %[v], 3\n\t" \
        "v_readlane_b32 %4, %[v], 4\n\t" \
        "v_readlane_b32 %5, %[v], 5\n\t" \
        "v_readlane_b32 %6, %[v], 6\n\t" \
        "v_readlane_b32 %7, %[v], 7\n\t" \
        "v_readlane_b32 %8, %[v], 8\n\t" \
        "v_readlane_b32 %9, %[v], 9\n\t" \
        "v_readlane_b32 %10, %[v], 10\n\t" \
        "v_readlane_b32 %11, %[v], 11\n\t" \
        "v_readlane_b32 %12, %[v], 12\n\t" \
        "v_readlane_b32 %13, %[v], 13\n\t" \
        "v_readlane_b32 %14, %[v], 14\n\t" \
        "v_readlane_b32 %15, %[v], 15\n\t" \
        "v_readlane_b32 %16, %[v], 16\n\t" \
        "v_readlane_b32 %17, %[v], 17\n\t" \
        "v_readlane_b32 %18, %[v], 18\n\t" \
        "v_readlane_b32 %19, %[v], 19\n\t" \
        "v_readlane_b32 %20, %[v], 20\n\t" \
        : "=s"(A[0]),"=s"(A[1]),"=s"(A[2]),"=s"(A[3]),"=s"(A[4]), \
          "=s"(A[5]),"=s"(A[6]),"=s"(A[7]),"=s"(A[8]),"=s"(A[9]), \
          "=s"(A[10]),"=s"(A[11]),"=s"(A[12]),"=s"(A[13]),"=s"(A[14]), \
          "=s"(A[15]),"=s"(A[16]),"=s"(A[17]),"=s"(A[18]),"=s"(A[19]), \
          "=s"(A[20]) \
        : [v]"v"(src))

// ---------------- emissions = hidden @ W + b  (split-K x4, LDS combine) ----------------
__global__ __launch_bounds__(256) void emis_kernel(
    const float* __restrict__ hidden, const float* __restrict__ W,
    const float* __restrict__ bias, float* __restrict__ em)
{
    __shared__ float part[4][64][22];
    const int lane = threadIdx.x & 63;
    const int w    = threadIdx.x >> 6;
    const int row  = blockIdx.x*64 + lane;
    const int wb   = 64 + (lane < 20 ? lane : 19);
    const float4* h4 = (const float4*)(hidden + (size_t)row*Hn) + w*48;
    const float*  Wp = W + w*(192*Ln);
    float acc[Ln];
    #pragma unroll
    for (int j=0;j<Ln;++j) acc[j]=0.f;
    float4 hcur = h4[0];
    float Wa = Wp[lane], Wb2 = Wp[wb];
    for (int t=0;t<48;++t){
        float4 hn = hcur; float Wan = Wa, Wbn = Wb2;
        if (t<47){ hn = h4[t+1]; Wan = Wp[(t+1)*84+lane]; Wbn = Wp[(t+1)*84+wb]; }
        const float* hv = &hcur.x;
        #pragma unroll
        for (int c=0;c<4;++c){
            float x = hv[c];
            #pragma unroll
            for (int j=0;j<Ln;++j){
                const int idx = c*Ln+j;
                float wv = (idx<64) ? rl(Wa, idx) : rl(Wb2, idx-64);
                acc[j] = fmaf(x, wv, acc[j]);
            }
        }
        hcur=hn; Wa=Wan; Wb2=Wbn;
    }
    #pragma unroll
    for (int j=0;j<Ln;++j) part[w][lane][j] = acc[j];
    __syncthreads();
    float* ob = em + (size_t)blockIdx.x*64*Ln;
    for (int e=threadIdx.x; e<64*Ln; e+=256){
        int r = e/Ln, j = e-r*Ln;
        ob[e] = ((part[0][r][j]+part[1][r][j])+(part[2][r][j]+part[3][r][j])) + bias[j];
    }
}

// ---------------- scan: 1 block per batch; wave0 = viterbi, wave1 = NLL; em in LDS ----------------
__global__ __launch_bounds__(128) void scan_kernel(
    const float* __restrict__ em, const int* __restrict__ labels,
    const int* __restrict__ amask, const float* __restrict__ st,
    const float* __restrict__ et, const float* __restrict__ trans,
    float* __restrict__ ws, float* __restrict__ alf)
{
    __shared__ float em_s[(Tn+2)*Ln];   // rows 512,513 duplicate row 511 (prefetch, no clamp)

    const int b    = blockIdx.x;
    const int tid  = threadIdx.x;
    const int wv   = tid >> 6;
    const int lane = tid & 63;
    const float* emb = em + (size_t)b*Tn*Ln;

    for (int i=tid; i<Tn*Ln; i+=128) em_s[i] = emb[i];
    for (int i=tid; i<2*Ln; i+=128){
        int jj = (i < Ln) ? i : (i - Ln);
        em_s[Tn*Ln + i] = emb[(Tn-1)*Ln + jj];
    }
    __syncthreads();

    const bool act = (lane < Ln);
    const int  j   = act ? lane : 0;

    if (wv == 0){
        // ---- Viterbi forward: value recurrence; alpha streamed into logits region ----
        const int* mk = amask + b*Tn;
        unsigned long long mb[8];
        #pragma unroll
        for (int c=0;c<8;++c) mb[c] = __ballot(mk[c*64 + lane] != 0);

        float trc[Ln];
        #pragma unroll
        for (int i=0;i<Ln;++i) trc[i] = trans[i*Ln + j];

        float sc = act ? (st[j] + em_s[j]) : -1e30f;
        float* sp = act ? (alf + (size_t)b*Tn*Ln + j) : (ws + DUMP_OFF + lane);
        const int sstep = act ? Ln : 0;
        *sp = sc; sp += sstep;

        const float* ep = &em_s[Ln + j];
        float e1 = ep[0]; ep += Ln;       // t=1
        float e2 = ep[0]; ep += Ln;       // t=2; ep -> row 3

        #pragma unroll
        for (int c=0;c<8;++c){
            const unsigned long long m = mb[c];
            for (int tt = (c==0 ? 1 : 0); tt < 64; ++tt){
                float ec = e1; e1 = e2;
                e2 = ep[0]; ep += Ln;              // prefetch t+2 (rows extended)
                float A[Ln];
                READLANES(sc, A);
                float v0=A[0]+trc[0],  v1=A[1]+trc[1],  v2=A[2]+trc[2];
                float v3=A[3]+trc[3],  v4=A[4]+trc[4],  v5=A[5]+trc[5];
                float v6=A[6]+trc[6],  v7=A[7]+trc[7],  v8=A[8]+trc[8];
                float v9=A[9]+trc[9],  v10=A[10]+trc[10],v11=A[11]+trc[11];
                float v12=A[12]+trc[12],v13=A[13]+trc[13],v14=A[14]+trc[14];
                float v15=A[15]+trc[15],v16=A[16]+trc[16],v17=A[17]+trc[17];
                float v18=A[18]+trc[18],v19=A[19]+trc[19],v20=A[20]+trc[20];
                float a0 = fmaxf(fmaxf(v0,v1),v2);
                float a1 = fmaxf(fmaxf(v3,v4),v5);
                float a2 = fmaxf(fmaxf(v6,v7),v8);
                float a3 = fmaxf(fmaxf(v9,v10),v11);
                float a4 = fmaxf(fmaxf(v12,v13),v14);
                float a5 = fmaxf(fmaxf(v15,v16),v17);
                float a6 = fmaxf(fmaxf(v18,v19),v20);
                float b0 = fmaxf(fmaxf(a0,a1),a2);
                float b1 = fmaxf(fmaxf(a3,a4),a5);
                float best = fmaxf(fmaxf(b0,b1),a6);
                float scn = best + ec;
                int mc = (int)((m >> tt) & 1ull);
                sc = mc ? scn : sc;
                *sp = sc; sp += sstep;
            }
        }
        float val = act ? (sc + et[j]) : -1e30f;
        int   idx = act ? j : 1000;
        #pragma unroll
        for (int off=32; off>=1; off>>=1){
            float ov = __shfl_xor(val, off, 64);
            int   oi = __shfl_xor(idx, off, 64);
            if (ov > val || (ov==val && oi<idx)){ val=ov; idx=oi; }
        }
        if (lane==0) ((int*)(ws+TAG_OFF))[b] = idx;
    } else {
        // ---- NLL forward in scaled-prob domain ----
        const int* lb = labels + b*Tn;
        unsigned long long mb[8];
        #pragma unroll
        for (int c=0;c<8;++c) mb[c] = __ballot(lb[c*64 + lane] != -100);

        float Ec[Ln];
        #pragma unroll
        for (int i=0;i<Ln;++i) Ec[i] = __expf(trans[i*Ln + j]);

        float p = act ? __expf(st[j] + em_s[j]) : 0.f;
        float M = 0.f;

        const float* ep = &em_s[Ln + j];
        float e1 = ep[0]; ep += Ln;
        float e2 = ep[0]; ep += Ln;

        #pragma unroll
        for (int c=0;c<8;++c){
            const unsigned long long m = mb[c];
            for (int tt = (c==0 ? 1 : 0); tt < 64; ++tt){
                float ec = e1; e1 = e2;
                e2 = ep[0]; ep += Ln;
                float pe = __expf(ec);
                float A[Ln];
                READLANES(p, A);
                float s0=0.f,s1=0.f,s2=0.f;
                #pragma unroll
                for (int i=0;i<Ln;++i){
                    if      (i%3==0) s0 = fmaf(A[i], Ec[i], s0);
                    else if (i%3==1) s1 = fmaf(A[i], Ec[i], s1);
                    else             s2 = fmaf(A[i], Ec[i], s2);
                }
                float pn = ((s0+s1)+s2) * pe;
                int lc = (int)((m >> tt) & 1ull);
                p = lc ? pn : p;
                if ((tt & 7) == 0){
                    float p0 = rl(p,0);
                    int e; frexpf(p0, &e);
                    p = ldexpf(p, -e);
                    M += (float)e * 0.6931471805599453f;
                }
            }
        }
        float val = act ? (p * __expf(et[j])) : 0.f;
        #pragma unroll
        for (int off=32; off>=1; off>>=1) val += __shfl_xor(val, off, 64);
        if (lane==0) (ws+LZ_OFF)[b] = M + __logf(val);
    }
}

// ---------------- post: blocks 0..63 bp-recompute+backtrack+logits; 64..127 gold score ----------------
__global__ __launch_bounds__(512) void post_kernel(
    const float* __restrict__ em, const int* __restrict__ labels,
    const int* __restrict__ amask, const float* __restrict__ st,
    const float* __restrict__ et, const float* __restrict__ trans,
    float* __restrict__ ws, float* __restrict__ logits)
{
    const int b    = blockIdx.x & (Bn-1);
    const int mode = blockIdx.x >> 6;
    const int tid  = threadIdx.x;

    if (mode == 0){
        __shared__ unsigned char hist_s[Tn*Ln];
        __shared__ int lab_s[Tn];
        __shared__ int path_s[Tn];
        __shared__ unsigned char comp_s[64*Ln];
        __shared__ unsigned char ent_s[64];
        lab_s[tid] = amask[b*Tn + tid];
        const int w = tid >> 6, lane = tid & 63;
        const bool act = lane < Ln;
        const int jc = act ? lane : 0;
        float trc[Ln];
        #pragma unroll
        for (int i=0;i<Ln;++i) trc[i] = trans[i*Ln + jc];
        __syncthreads();
        const float* alf = logits + (size_t)b*Tn*Ln;   // alpha lives here (from scan)
        for (int t = 1+w; t < Tn; t += 8){
            const float* ar = alf + (size_t)(t-1)*Ln;
            float a[Ln];
            #pragma unroll
            for (int i=0;i<Ln;++i) a[i] = ar[i];
            int bp = lane;
            if (lab_s[t]){
                float v[Ln];
                #pragma unroll
                for (int i=0;i<Ln;++i) v[i] = a[i] + trc[i];
                float a0 = fmaxf(fmaxf(v[0],v[1]),v[2]);
                float a1 = fmaxf(fmaxf(v[3],v[4]),v[5]);
                float a2 = fmaxf(fmaxf(v[6],v[7]),v[8]);
                float a3 = fmaxf(fmaxf(v[9],v[10]),v[11]);
                float a4 = fmaxf(fmaxf(v[12],v[13]),v[14]);
                float a5 = fmaxf(fmaxf(v[15],v[16]),v[17]);
                float a6 = fmaxf(fmaxf(v[18],v[19]),v[20]);
                float b0 = fmaxf(fmaxf(a0,a1),a2);
                float b1 = fmaxf(fmaxf(a3,a4),a5);
                float best = fmaxf(fmaxf(b0,b1),a6);
                unsigned bm = 0u;
                #pragma unroll
                for (int i=0;i<Ln;++i) bm |= (v[i]==best) ? (1u<<i) : 0u;
                bp = __ffs(bm) - 1;
            }
            if (act) hist_s[t*Ln + lane] = (unsigned char)bp;
        }
        __syncthreads();
        if (tid < 64){
            unsigned char cur[Ln];
            #pragma unroll
            for (int q=0;q<Ln;++q) cur[q] = (unsigned char)q;
            #pragma unroll
            for (int k=8;k>=1;--k){
                int ta = 8*tid + k;
                if (ta < Tn){
                    const unsigned char* hr = &hist_s[ta*Ln];
                    #pragma unroll
                    for (int q=0;q<Ln;++q) cur[q] = hr[cur[q]];
                }
            }
            #pragma unroll
            for (int q=0;q<Ln;++q) comp_s[tid*Ln+q] = cur[q];
        }
        __syncthreads();
        if (tid==0){
            int cg = ((const int*)(ws+TAG_OFF))[b];
            for (int l=63;l>=0;--l){ ent_s[l]=(unsigned char)cg; cg = comp_s[l*Ln+cg]; }
        }
        __syncthreads();
        if (tid < 64){
            int s = ent_s[tid];
            if (tid==63) path_s[Tn-1] = s;
            #pragma unroll
            for (int k=8;k>=1;--k){
                int ta = 8*tid + k;
                if (ta < Tn){ s = hist_s[ta*Ln+s]; path_s[ta-1] = s; }
            }
        }
        __syncthreads();   // all alpha reads done; overwrite with one-hot
        float* lg = logits + (size_t)b*Tn*Ln;
        for (int id2=tid; id2<Tn*Ln; id2+=512){
            int t = id2/Ln; int jj = id2 - t*Ln;
            lg[id2] = (lab_s[t] && path_s[t]==jj) ? 1.0f : 0.0f;
        }
    } else {
        __shared__ float red_s[8];
        __shared__ int  redc_s[8];
        const int* lb = labels + b*Tn;
        int labt = lb[tid];
        float term = 0.f;
        int c = (tid==0 || labt != -100) ? 1 : 0;
        if (tid>=1 && labt != -100){
            int lp = lb[tid-1]; if (lp<0) lp=0;
            term = trans[lp*Ln+labt] + em[((size_t)b*Tn+tid)*Ln + labt];
        }
        #pragma unroll
        for (int off=32; off>=1; off>>=1){
            term += __shfl_xor(term, off, 64);
            c    += __shfl_xor(c,    off, 64);
        }
        int w = tid>>6;
        if ((tid&63)==0){ red_s[w]=term; redc_s[w]=c; }
        __syncthreads();
        if (tid==0){
            float sum=0.f; int cnt=0;
            #pragma unroll
            for (int q=0;q<8;++q){ sum+=red_s[q]; cnt+=redc_s[q]; }
            int l0 = lb[0]; int tag0 = l0<0?0:l0;
            float score = st[tag0] + em[(size_t)b*Tn*Ln + tag0] + sum;
            int li = cnt-1; int ll = lb[li]; int lt = ll<0?0:ll;
            score += et[lt];
            (ws+DIFF_OFF)[b] = score - (ws+LZ_OFF)[b];
        }
    }
}

// ---------------- finalize: nll = -mean(score - logZ) ----------------
__global__ __launch_bounds__(64) void fin_kernel(const float* __restrict__ ws,
                                                 float* __restrict__ out0)
{
    float v = (ws+DIFF_OFF)[threadIdx.x];
    #pragma unroll
    for (int off=32; off>=1; off>>=1) v += __shfl_xor(v, off, 64);
    if (threadIdx.x==0) out0[0] = -(v * (1.0f/64.0f));
}

extern "C" void kernel_launch(void* const* d_in, const int* in_sizes, int n_in,
                              void* d_out, int out_size, void* d_ws, size_t ws_size,
                              hipStream_t stream)
{
    (void)in_sizes; (void)n_in; (void)out_size; (void)ws_size;
    const float* hidden = (const float*)d_in[0];
    const float* W      = (const float*)d_in[1];
    const float* bias   = (const float*)d_in[2];
    const float* st     = (const float*)d_in[3];
    const float* et     = (const float*)d_in[4];
    const float* trans  = (const float*)d_in[5];
    const int*   labels = (const int*)d_in[6];
    const int*   amask  = (const int*)d_in[7];

    float* out    = (float*)d_out;
    float* nll    = out;
    float* logits = out + 1;
    float* em     = out + 1 + EM_ELEMS;
    float* ws     = (float*)d_ws;

    emis_kernel<<<dim3(Bn*Tn/64), dim3(256), 0, stream>>>(hidden, W, bias, em);
    scan_kernel<<<dim3(Bn), dim3(128), 0, stream>>>(em, labels, amask, st, et, trans, ws, logits);
    post_kernel<<<dim3(2*Bn), dim3(512), 0, stream>>>(em, labels, amask, st, et, trans, ws, logits);
    fin_kernel<<<dim3(1), dim3(64), 0, stream>>>(ws, nll);
}

// Round 8
// 162.701 us; speedup vs baseline: 1.6719x; 1.0042x over previous
//
#include <hip/hip_runtime.h>

#define Bn 64
#define Tn 512
#define Hn 768
#define Ln 21
#define EM_ELEMS (Bn*Tn*Ln)

// tiny ws layout (floats)
#define DUMP_OFF 0
#define LZ_OFF   64
#define TAG_OFF  128
#define DIFF_OFF 192

__device__ __forceinline__ float rl(float x, int i){
    return __int_as_float(__builtin_amdgcn_readlane(__float_as_int(x), i));
}
// wave_ror:1 — each lane receives its neighbor's value (64-lane rotate), pure VALU
__device__ __forceinline__ float ror1f(float x){
    return __int_as_float(__builtin_amdgcn_mov_dpp(__float_as_int(x), 0x13C, 0xF, 0xF, true));
}

// ---------------- emissions = hidden @ W + b  (split-K x4, LDS combine) ----------------
__global__ __launch_bounds__(256) void emis_kernel(
    const float* __restrict__ hidden, const float* __restrict__ W,
    const float* __restrict__ bias, float* __restrict__ em)
{
    __shared__ float part[4][64][22];
    const int lane = threadIdx.x & 63;
    const int w    = threadIdx.x >> 6;
    const int row  = blockIdx.x*64 + lane;
    const int wb   = 64 + (lane < 20 ? lane : 19);
    const float4* h4 = (const float4*)(hidden + (size_t)row*Hn) + w*48;
    const float*  Wp = W + w*(192*Ln);
    float acc[Ln];
    #pragma unroll
    for (int j=0;j<Ln;++j) acc[j]=0.f;
    float4 hcur = h4[0];
    float Wa = Wp[lane], Wb2 = Wp[wb];
    for (int t=0;t<48;++t){
        float4 hn = hcur; float Wan = Wa, Wbn = Wb2;
        if (t<47){ hn = h4[t+1]; Wan = Wp[(t+1)*84+lane]; Wbn = Wp[(t+1)*84+wb]; }
        const float* hv = &hcur.x;
        #pragma unroll
        for (int c=0;c<4;++c){
            float x = hv[c];
            #pragma unroll
            for (int j=0;j<Ln;++j){
                const int idx = c*Ln+j;
                float wv = (idx<64) ? rl(Wa, idx) : rl(Wb2, idx-64);
                acc[j] = fmaf(x, wv, acc[j]);
            }
        }
        hcur=hn; Wa=Wan; Wb2=Wbn;
    }
    #pragma unroll
    for (int j=0;j<Ln;++j) part[w][lane][j] = acc[j];
    __syncthreads();
    float* ob = em + (size_t)blockIdx.x*64*Ln;
    for (int e=threadIdx.x; e<64*Ln; e+=256){
        int r = e/Ln, j = e-r*Ln;
        ob[e] = ((part[0][r][j]+part[1][r][j])+(part[2][r][j]+part[3][r][j])) + bias[j];
    }
}

// ---------------- scan: 1 block per batch; wave0 = viterbi, wave1 = NLL; em in LDS ----------------
// alpha replicated as beta_L = alpha_{L mod 21}; broadcast via 21x wave_ror:1 DPP chain.
__global__ __launch_bounds__(128) void scan_kernel(
    const float* __restrict__ em, const int* __restrict__ labels,
    const int* __restrict__ amask, const float* __restrict__ st,
    const float* __restrict__ et, const float* __restrict__ trans,
    float* __restrict__ ws, float* __restrict__ alf)
{
    __shared__ float em_s[(Tn+2)*Ln];   // rows 512,513 duplicate row 511 (prefetch, no clamp)

    const int b    = blockIdx.x;
    const int tid  = threadIdx.x;
    const int wv   = tid >> 6;
    const int lane = tid & 63;
    const float* emb = em + (size_t)b*Tn*Ln;

    for (int i=tid; i<Tn*Ln; i+=128) em_s[i] = emb[i];
    for (int i=tid; i<2*Ln; i+=128){
        int jj = (i < Ln) ? i : (i - Ln);
        em_s[Tn*Ln + i] = emb[(Tn-1)*Ln + jj];
    }
    __syncthreads();

    const int  j   = lane % Ln;            // lane 63 -> 0 (64 = 3*21+1)
    const bool act = (lane < Ln);

    // rotation-order source-index table, derived from the ACTUAL DPP permutation
    int idxs[22];
    {
        int rid = lane; idxs[0] = j;
        #pragma unroll
        for (int p=1;p<=21;++p){
            rid = __builtin_amdgcn_mov_dpp(rid, 0x13C, 0xF, 0xF, true);
            idxs[p] = rid % Ln;
        }
    }

    if (wv == 0){
        // ---- Viterbi forward ----
        float tt[22];
        #pragma unroll
        for (int p=0;p<=21;++p) tt[p] = trans[idxs[p]*Ln + j];   // T[i_src][j]

        const int* mk = amask + b*Tn;
        unsigned long long mb[8];
        #pragma unroll
        for (int c=0;c<8;++c) mb[c] = __ballot(mk[c*64 + lane] != 0);

        float sc = st[j] + em_s[j];        // replicated, identical across copies
        float* sp = act ? (alf + (size_t)b*Tn*Ln + j) : (ws + DUMP_OFF + lane);
        const int sstep = act ? Ln : 0;
        *sp = sc; sp += sstep;

        const float* epr = &em_s[Ln + j];
        float e1 = epr[0]; epr += Ln;
        float e2 = epr[0]; epr += Ln;

        #pragma unroll
        for (int c=0;c<8;++c){
            const unsigned long long m = mb[c];
            for (int q = (c==0 ? 1 : 0); q < 64; ++q){
                float ec = e1; e1 = e2;
                e2 = epr[0]; epr += Ln;
                float r  = sc;
                float a0 = sc + tt[0];
                float a1 = -1e30f, a2 = -1e30f;
                #pragma unroll
                for (int p=1;p<=21;++p){
                    r = ror1f(r);
                    float v = r + tt[p];
                    if      (p%3==1) a0 = fmaxf(a0, v);
                    else if (p%3==2) a1 = fmaxf(a1, v);
                    else             a2 = fmaxf(a2, v);
                }
                float best = fmaxf(fmaxf(a0,a1),a2);
                float scn = best + ec;
                int mc = (int)((m >> q) & 1ull);
                sc = mc ? scn : sc;
                *sp = sc; sp += sstep;
            }
        }
        float val = act ? (sc + et[j]) : -1e30f;
        int   idx = act ? j : 1000;
        #pragma unroll
        for (int off=32; off>=1; off>>=1){
            float ov = __shfl_xor(val, off, 64);
            int   oi = __shfl_xor(idx, off, 64);
            if (ov > val || (ov==val && oi<idx)){ val=ov; idx=oi; }
        }
        if (lane==0) ((int*)(ws+TAG_OFF))[b] = idx;
    } else {
        // ---- NLL forward in scaled-prob domain ----
        float wt[22];
        {
            unsigned seen = 0u;
            #pragma unroll
            for (int p=0;p<=21;++p){
                int i = idxs[p];
                bool dup = (seen >> i) & 1u;
                seen |= (1u << i);
                wt[p] = dup ? 0.f : __expf(trans[i*Ln + j]);
            }
        }
        const int* lb = labels + b*Tn;
        unsigned long long mb[8];
        #pragma unroll
        for (int c=0;c<8;++c) mb[c] = __ballot(lb[c*64 + lane] != -100);

        float pv = __expf(st[j] + em_s[j]);
        float M = 0.f;

        const float* epr = &em_s[Ln + j];
        float e1 = epr[0]; epr += Ln;
        float e2 = epr[0]; epr += Ln;

        #pragma unroll
        for (int c=0;c<8;++c){
            const unsigned long long m = mb[c];
            for (int q = (c==0 ? 1 : 0); q < 64; ++q){
                float ec = e1; e1 = e2;
                e2 = epr[0]; epr += Ln;
                float pe = __expf(ec);
                float r  = pv;
                float s0 = pv * wt[0], s1 = 0.f, s2 = 0.f;
                #pragma unroll
                for (int p=1;p<=21;++p){
                    r = ror1f(r);
                    if      (p%3==1) s0 = fmaf(r, wt[p], s0);
                    else if (p%3==2) s1 = fmaf(r, wt[p], s1);
                    else             s2 = fmaf(r, wt[p], s2);
                }
                float pn = ((s0+s1)+s2) * pe;
                int lc = (int)((m >> q) & 1ull);
                pv = lc ? pn : pv;
                if ((q & 7) == 0){
                    float p0 = rl(pv, 0);
                    int e; frexpf(p0, &e);
                    pv = ldexpf(pv, -e);
                    M += (float)e * 0.6931471805599453f;
                }
            }
        }
        float val = act ? (pv * __expf(et[j])) : 0.f;
        #pragma unroll
        for (int off=32; off>=1; off>>=1) val += __shfl_xor(val, off, 64);
        if (lane==0) (ws+LZ_OFF)[b] = M + __logf(val);
    }
}

// ---------------- post: blocks 0..63 bp-recompute+backtrack+logits; 64..127 gold score ----------------
__global__ __launch_bounds__(512) void post_kernel(
    const float* __restrict__ em, const int* __restrict__ labels,
    const int* __restrict__ amask, const float* __restrict__ st,
    const float* __restrict__ et, const float* __restrict__ trans,
    float* __restrict__ ws, float* __restrict__ logits)
{
    const int b    = blockIdx.x & (Bn-1);
    const int mode = blockIdx.x >> 6;
    const int tid  = threadIdx.x;

    if (mode == 0){
        __shared__ unsigned char hist_s[Tn*Ln];
        __shared__ int lab_s[Tn];
        __shared__ int path_s[Tn];
        __shared__ unsigned char comp_s[64*Ln];
        __shared__ unsigned char ent_s[64];
        lab_s[tid] = amask[b*Tn + tid];
        const int w = tid >> 6, lane = tid & 63;
        const bool act = lane < Ln;
        const int jc = act ? lane : 0;
        float trc[Ln];
        #pragma unroll
        for (int i=0;i<Ln;++i) trc[i] = trans[i*Ln + jc];
        __syncthreads();
        const float* alf = logits + (size_t)b*Tn*Ln;   // alpha lives here (from scan)
        for (int t = 1+w; t < Tn; t += 8){
            const float* ar = alf + (size_t)(t-1)*Ln;
            float a[Ln];
            #pragma unroll
            for (int i=0;i<Ln;++i) a[i] = ar[i];
            int bp = lane;
            if (lab_s[t]){
                float v[Ln];
                #pragma unroll
                for (int i=0;i<Ln;++i) v[i] = a[i] + trc[i];
                float a0 = fmaxf(fmaxf(v[0],v[1]),v[2]);
                float a1 = fmaxf(fmaxf(v[3],v[4]),v[5]);
                float a2 = fmaxf(fmaxf(v[6],v[7]),v[8]);
                float a3 = fmaxf(fmaxf(v[9],v[10]),v[11]);
                float a4 = fmaxf(fmaxf(v[12],v[13]),v[14]);
                float a5 = fmaxf(fmaxf(v[15],v[16]),v[17]);
                float a6 = fmaxf(fmaxf(v[18],v[19]),v[20]);
                float b0 = fmaxf(fmaxf(a0,a1),a2);
                float b1 = fmaxf(fmaxf(a3,a4),a5);
                float best = fmaxf(fmaxf(b0,b1),a6);
                unsigned bm = 0u;
                #pragma unroll
                for (int i=0;i<Ln;++i) bm |= (v[i]==best) ? (1u<<i) : 0u;
                bp = __ffs(bm) - 1;
            }
            if (act) hist_s[t*Ln + lane] = (unsigned char)bp;
        }
        __syncthreads();
        if (tid < 64){
            unsigned char cur[Ln];
            #pragma unroll
            for (int q=0;q<Ln;++q) cur[q] = (unsigned char)q;
            #pragma unroll
            for (int k=8;k>=1;--k){
                int ta = 8*tid + k;
                if (ta < Tn){
                    const unsigned char* hr = &hist_s[ta*Ln];
                    #pragma unroll
                    for (int q=0;q<Ln;++q) cur[q] = hr[cur[q]];
                }
            }
            #pragma unroll
            for (int q=0;q<Ln;++q) comp_s[tid*Ln+q] = cur[q];
        }
        __syncthreads();
        if (tid==0){
            int cg = ((const int*)(ws+TAG_OFF))[b];
            for (int l=63;l>=0;--l){ ent_s[l]=(unsigned char)cg; cg = comp_s[l*Ln+cg]; }
        }
        __syncthreads();
        if (tid < 64){
            int s = ent_s[tid];
            if (tid==63) path_s[Tn-1] = s;
            #pragma unroll
            for (int k=8;k>=1;--k){
                int ta = 8*tid + k;
                if (ta < Tn){ s = hist_s[ta*Ln+s]; path_s[ta-1] = s; }
            }
        }
        __syncthreads();   // all alpha reads done; overwrite with one-hot
        float* lg = logits + (size_t)b*Tn*Ln;
        for (int id2=tid; id2<Tn*Ln; id2+=512){
            int t = id2/Ln; int jj = id2 - t*Ln;
            lg[id2] = (lab_s[t] && path_s[t]==jj) ? 1.0f : 0.0f;
        }
    } else {
        __shared__ float red_s[8];
        __shared__ int  redc_s[8];
        const int* lb = labels + b*Tn;
        int labt = lb[tid];
        float term = 0.f;
        int c = (tid==0 || labt != -100) ? 1 : 0;
        if (tid>=1 && labt != -100){
            int lp = lb[tid-1]; if (lp<0) lp=0;
            term = trans[lp*Ln+labt] + em[((size_t)b*Tn+tid)*Ln + labt];
        }
        #pragma unroll
        for (int off=32; off>=1; off>>=1){
            term += __shfl_xor(term, off, 64);
            c    += __shfl_xor(c,    off, 64);
        }
        int w = tid>>6;
        if ((tid&63)==0){ red_s[w]=term; redc_s[w]=c; }
        __syncthreads();
        if (tid==0){
            float sum=0.f; int cnt=0;
            #pragma unroll
            for (int q=0;q<8;++q){ sum+=red_s[q]; cnt+=redc_s[q]; }
            int l0 = lb[0]; int tag0 = l0<0?0:l0;
            float score = st[tag0] + em[(size_t)b*Tn*Ln + tag0] + sum;
            int li = cnt-1; int ll = lb[li]; int lt = ll<0?0:ll;
            score += et[lt];
            (ws+DIFF_OFF)[b] = score - (ws+LZ_OFF)[b];
        }
    }
}

// ---------------- finalize: nll = -mean(score - logZ) ----------------
__global__ __launch_bounds__(64) void fin_kernel(const float* __restrict__ ws,
                                                 float* __restrict__ out0)
{
    float v = (ws+DIFF_OFF)[threadIdx.x];
    #pragma unroll
    for (int off=32; off>=1; off>>=1) v += __shfl_xor(v, off, 64);
    if (threadIdx.x==0) out0[0] = -(v * (1.0f/64.0f));
}

extern "C" void kernel_launch(void* const* d_in, const int* in_sizes, int n_in,
                              void* d_out, int out_size, void* d_ws, size_t ws_size,
                              hipStream_t stream)
{
    (void)in_sizes; (void)n_in; (void)out_size; (void)ws_size;
    const float* hidden = (const float*)d_in[0];
    const float* W      = (const float*)d_in[1];
    const float* bias   = (const float*)d_in[2];
    const float* st     = (const float*)d_in[3];
    const float* et     = (const float*)d_in[4];
    const float* trans  = (const float*)d_in[5];
    const int*   labels = (const int*)d_in[6];
    const int*   amask  = (const int*)d_in[7];

    float* out    = (float*)d_out;
    float* nll    = out;
    float* logits = out + 1;
    float* em     = out + 1 + EM_ELEMS;
    float* ws     = (float*)d_ws;

    emis_kernel<<<dim3(Bn*Tn/64), dim3(256), 0, stream>>>(hidden, W, bias, em);
    scan_kernel<<<dim3(Bn), dim3(128), 0, stream>>>(em, labels, amask, st, et, trans, ws, logits);
    post_kernel<<<dim3(2*Bn), dim3(512), 0, stream>>>(em, labels, amask, st, et, trans, ws, logits);
    fin_kernel<<<dim3(1), dim3(64), 0, stream>>>(ws, nll);
}

// Round 11
// 154.557 us; speedup vs baseline: 1.7600x; 1.0527x over previous
//
#include <hip/hip_runtime.h>

#define Bn 64
#define Tn 512
#define Hn 768
#define Ln 21
#define EM_ELEMS (Bn*Tn*Ln)

// ws layout (floats)
#define DIFF_OFF 192

__device__ __forceinline__ float rl(float x, int i){
    return __int_as_float(__builtin_amdgcn_readlane(__float_as_int(x), i));
}

// 21 readlanes into 21 DISTINCT SGPRs in one asm block (pipelined, no SGPR reuse hazard)
// NOTE: loops containing this macro MUST stay rolled — 8x unrolling it miscompiled (r9/r10: inf).
#define READLANES(src, A) \
    asm volatile( \
        "v_readlane_b32 %0, %[v], 0\n\t" \
        "v_readlane_b32 %1, %[v], 1\n\t" \
        "v_readlane_b32 %2, %[v], 2\n\t" \
        "v_readlane_b32 %3, %[v], 3\n\t" \
        "v_readlane_b32 %4, %[v], 4\n\t" \
        "v_readlane_b32 %5, %[v], 5\n\t" \
        "v_readlane_b32 %6, %[v], 6\n\t" \
        "v_readlane_b32 %7, %[v], 7\n\t" \
        "v_readlane_b32 %8, %[v], 8\n\t" \
        "v_readlane_b32 %9, %[v], 9\n\t" \
        "v_readlane_b32 %10, %[v], 10\n\t" \
        "v_readlane_b32 %11, %[v], 11\n\t" \
        "v_readlane_b32 %12, %[v], 12\n\t" \
        "v_readlane_b32 %13, %[v], 13\n\t" \
        "v_readlane_b32 %14, %[v], 14\n\t" \
        "v_readlane_b32 %15, %[v], 15\n\t" \
        "v_readlane_b32 %16, %[v], 16\n\t" \
        "v_readlane_b32 %17, %[v], 17\n\t" \
        "v_readlane_b32 %18, %[v], 18\n\t" \
        "v_readlane_b32 %19, %[v], 19\n\t" \
        "v_readlane_b32 %20, %[v], 20\n\t" \
        : "=s"(A[0]),"=s"(A[1]),"=s"(A[2]),"=s"(A[3]),"=s"(A[4]), \
          "=s"(A[5]),"=s"(A[6]),"=s"(A[7]),"=s"(A[8]),"=s"(A[9]), \
          "=s"(A[10]),"=s"(A[11]),"=s"(A[12]),"=s"(A[13]),"=s"(A[14]), \
          "=s"(A[15]),"=s"(A[16]),"=s"(A[17]),"=s"(A[18]),"=s"(A[19]), \
          "=s"(A[20]) \
        : [v]"v"(src))

// ---------------- emissions = hidden @ W + b  (split-K x4, LDS combine) ----------------
__global__ __launch_bounds__(256) void emis_kernel(
    const float* __restrict__ hidden, const float* __restrict__ W,
    const float* __restrict__ bias, float* __restrict__ em)
{
    __shared__ float part[4][64][22];
    const int lane = threadIdx.x & 63;
    const int w    = threadIdx.x >> 6;
    const int row  = blockIdx.x*64 + lane;
    const int wb   = 64 + (lane < 20 ? lane : 19);
    const float4* h4 = (const float4*)(hidden + (size_t)row*Hn) + w*48;
    const float*  Wp = W + w*(192*Ln);
    float acc[Ln];
    #pragma unroll
    for (int j=0;j<Ln;++j) acc[j]=0.f;
    float4 hcur = h4[0];
    float Wa = Wp[lane], Wb2 = Wp[wb];
    for (int t=0;t<48;++t){
        float4 hn = hcur; float Wan = Wa, Wbn = Wb2;
        if (t<47){ hn = h4[t+1]; Wan = Wp[(t+1)*84+lane]; Wbn = Wp[(t+1)*84+wb]; }
        const float* hv = &hcur.x;
        #pragma unroll
        for (int c=0;c<4;++c){
            float x = hv[c];
            #pragma unroll
            for (int j=0;j<Ln;++j){
                const int idx = c*Ln+j;
                float wv = (idx<64) ? rl(Wa, idx) : rl(Wb2, idx-64);
                acc[j] = fmaf(x, wv, acc[j]);
            }
        }
        hcur=hn; Wa=Wan; Wb2=Wbn;
    }
    #pragma unroll
    for (int j=0;j<Ln;++j) part[w][lane][j] = acc[j];
    __syncthreads();
    float* ob = em + (size_t)blockIdx.x*64*Ln;
    for (int e=threadIdx.x; e<64*Ln; e+=256){
        int r = e/Ln, j = e-r*Ln;
        ob[e] = ((part[0][r][j]+part[1][r][j])+(part[2][r][j]+part[3][r][j])) + bias[j];
    }
}

// ---------------- fused: 1 block per batch; wave0 viterbi, wave1 NLL, wave2 gold score;
//                  then all 8 waves: bp recompute + backtrack + one-hot logits ----------------
__global__ __launch_bounds__(512) void fused_kernel(
    const float* __restrict__ em, const int* __restrict__ labels,
    const int* __restrict__ amask, const float* __restrict__ st,
    const float* __restrict__ et, const float* __restrict__ trans,
    float* __restrict__ ws, float* __restrict__ logits)
{
    __shared__ float em_s[(Tn+2)*Ln];        // rows 512,513 duplicate row 511 (prefetch, no clamp)
    __shared__ float alpha_s[Tn*Ln];         // viterbi alpha stream
    __shared__ unsigned char hist_s[Tn*Ln];
    __shared__ int   lab2_s[Tn];             // attention mask
    __shared__ int   path_s[Tn];
    __shared__ unsigned char comp_s[64*Ln];
    __shared__ unsigned char ent_s[64];
    __shared__ float dump_s[64];
    __shared__ float logZ_s, score_s;
    __shared__ int   tag_s;

    const int b    = blockIdx.x;
    const int tid  = threadIdx.x;
    const int wv   = tid >> 6;
    const int lane = tid & 63;
    const float* emb = em + (size_t)b*Tn*Ln;

    for (int i=tid; i<Tn*Ln; i+=512) em_s[i] = emb[i];
    for (int i=tid; i<2*Ln; i+=512){
        int jj = (i < Ln) ? i : (i - Ln);
        em_s[Tn*Ln + i] = emb[(Tn-1)*Ln + jj];
    }
    lab2_s[tid] = amask[b*Tn + tid];
    __syncthreads();

    const bool act = (lane < Ln);
    const int  j   = act ? lane : 0;

    if (wv == 0){
        // ---- Viterbi forward (round-7 core verbatim; alpha -> LDS) ----
        const int* mk = amask + b*Tn;
        unsigned long long mb[8];
        #pragma unroll
        for (int c=0;c<8;++c) mb[c] = __ballot(mk[c*64 + lane] != 0);

        float trc[Ln];
        #pragma unroll
        for (int i=0;i<Ln;++i) trc[i] = trans[i*Ln + j];

        float sc = act ? (st[j] + em_s[j]) : -1e30f;
        float* sp = act ? (&alpha_s[j]) : (&dump_s[lane]);
        const int sstep = act ? Ln : 0;
        *sp = sc; sp += sstep;

        const float* ep = &em_s[Ln + j];
        float e1 = ep[0]; ep += Ln;       // t=1
        float e2 = ep[0]; ep += Ln;       // t=2; ep -> row 3

        #pragma unroll
        for (int c=0;c<8;++c){
            const unsigned long long m = mb[c];
            for (int tt = (c==0 ? 1 : 0); tt < 64; ++tt){
                float ec = e1; e1 = e2;
                e2 = ep[0]; ep += Ln;              // prefetch t+2 (rows extended)
                float A[21];
                READLANES(sc, A);
                float v0=A[0]+trc[0],  v1=A[1]+trc[1],  v2=A[2]+trc[2];
                float v3=A[3]+trc[3],  v4=A[4]+trc[4],  v5=A[5]+trc[5];
                float v6=A[6]+trc[6],  v7=A[7]+trc[7],  v8=A[8]+trc[8];
                float v9=A[9]+trc[9],  v10=A[10]+trc[10],v11=A[11]+trc[11];
                float v12=A[12]+trc[12],v13=A[13]+trc[13],v14=A[14]+trc[14];
                float v15=A[15]+trc[15],v16=A[16]+trc[16],v17=A[17]+trc[17];
                float v18=A[18]+trc[18],v19=A[19]+trc[19],v20=A[20]+trc[20];
                float a0 = fmaxf(fmaxf(v0,v1),v2);
                float a1 = fmaxf(fmaxf(v3,v4),v5);
                float a2 = fmaxf(fmaxf(v6,v7),v8);
                float a3 = fmaxf(fmaxf(v9,v10),v11);
                float a4 = fmaxf(fmaxf(v12,v13),v14);
                float a5 = fmaxf(fmaxf(v15,v16),v17);
                float a6 = fmaxf(fmaxf(v18,v19),v20);
                float b0 = fmaxf(fmaxf(a0,a1),a2);
                float b1 = fmaxf(fmaxf(a3,a4),a5);
                float best = fmaxf(fmaxf(b0,b1),a6);
                float scn = best + ec;
                int mc = (int)((m >> tt) & 1ull);
                sc = mc ? scn : sc;
                *sp = sc; sp += sstep;
            }
        }
        float val = act ? (sc + et[j]) : -1e30f;
        int   idx = act ? j : 1000;
        #pragma unroll
        for (int off=32; off>=1; off>>=1){
            float ov = __shfl_xor(val, off, 64);
            int   oi = __shfl_xor(idx, off, 64);
            if (ov > val || (ov==val && oi<idx)){ val=ov; idx=oi; }
        }
        if (lane==0) tag_s = idx;
    } else if (wv == 1){
        // ---- NLL forward in scaled-prob domain (round-7 core verbatim) ----
        const int* lb = labels + b*Tn;
        unsigned long long mb[8];
        #pragma unroll
        for (int c=0;c<8;++c) mb[c] = __ballot(lb[c*64 + lane] != -100);

        float Ec[Ln];
        #pragma unroll
        for (int i=0;i<Ln;++i) Ec[i] = __expf(trans[i*Ln + j]);

        float p = act ? __expf(st[j] + em_s[j]) : 0.f;
        float M = 0.f;

        const float* ep = &em_s[Ln + j];
        float e1 = ep[0]; ep += Ln;
        float e2 = ep[0]; ep += Ln;

        #pragma unroll
        for (int c=0;c<8;++c){
            const unsigned long long m = mb[c];
            for (int tt = (c==0 ? 1 : 0); tt < 64; ++tt){
                float ec = e1; e1 = e2;
                e2 = ep[0]; ep += Ln;
                float pe = __expf(ec);
                float A[21];
                READLANES(p, A);
                float s0=0.f,s1=0.f,s2=0.f;
                #pragma unroll
                for (int i=0;i<Ln;++i){
                    if      (i%3==0) s0 = fmaf(A[i], Ec[i], s0);
                    else if (i%3==1) s1 = fmaf(A[i], Ec[i], s1);
                    else             s2 = fmaf(A[i], Ec[i], s2);
                }
                float pn = ((s0+s1)+s2) * pe;
                int lc = (int)((m >> tt) & 1ull);
                p = lc ? pn : p;
                if ((tt & 7) == 0){
                    float p0 = rl(p, 0);
                    int e; frexpf(p0, &e);
                    p = ldexpf(p, -e);
                    M += (float)e * 0.6931471805599453f;
                }
            }
        }
        float val = act ? (p * __expf(et[j])) : 0.f;
        #pragma unroll
        for (int off=32; off>=1; off>>=1) val += __shfl_xor(val, off, 64);
        if (lane==0) logZ_s = M + __logf(val);
    } else if (wv == 2){
        // ---- gold score (runs concurrently with the scans) ----
        const int* lb = labels + b*Tn;
        float term = 0.f; int cnt = 0;
        #pragma unroll
        for (int k=0;k<8;++k){
            int t = lane + 64*k;
            int labt = lb[t];
            if (t==0 || labt != -100) cnt++;
            if (t>=1 && labt != -100){
                int lp = lb[t-1]; if (lp<0) lp=0;
                term += trans[lp*Ln+labt] + em_s[t*Ln+labt];
            }
        }
        #pragma unroll
        for (int off=32; off>=1; off>>=1){
            term += __shfl_xor(term, off, 64);
            cnt  += __shfl_xor(cnt,  off, 64);
        }
        if (lane==0){
            int l0 = lb[0]; int tag0 = l0<0?0:l0;
            float score = st[tag0] + em_s[tag0] + term;
            int li = cnt-1; int ll = lb[li]; int lt = ll<0?0:ll;
            score += et[lt];
            score_s = score;
        }
    }
    __syncthreads();   // alpha_s, tag_s, logZ_s, score_s ready

    // ---- bp recompute (post verbatim; alpha from LDS) ----
    {
        float trc2[Ln];
        #pragma unroll
        for (int i=0;i<Ln;++i) trc2[i] = trans[i*Ln + j];
        for (int t = 1+wv; t < Tn; t += 8){
            const float* ar = &alpha_s[(t-1)*Ln];
            float a[Ln];
            #pragma unroll
            for (int i=0;i<Ln;++i) a[i] = ar[i];
            int bp = lane;
            if (lab2_s[t]){
                float v[Ln];
                #pragma unroll
                for (int i=0;i<Ln;++i) v[i] = a[i] + trc2[i];
                float a0 = fmaxf(fmaxf(v[0],v[1]),v[2]);
                float a1 = fmaxf(fmaxf(v[3],v[4]),v[5]);
                float a2 = fmaxf(fmaxf(v[6],v[7]),v[8]);
                float a3 = fmaxf(fmaxf(v[9],v[10]),v[11]);
                float a4 = fmaxf(fmaxf(v[12],v[13]),v[14]);
                float a5 = fmaxf(fmaxf(v[15],v[16]),v[17]);
                float a6 = fmaxf(fmaxf(v[18],v[19]),v[20]);
                float b0 = fmaxf(fmaxf(a0,a1),a2);
                float b1 = fmaxf(fmaxf(a3,a4),a5);
                float best = fmaxf(fmaxf(b0,b1),a6);
                unsigned bm = 0u;
                #pragma unroll
                for (int i=0;i<Ln;++i) bm |= (v[i]==best) ? (1u<<i) : 0u;
                bp = __ffs(bm) - 1;
            }
            if (act) hist_s[t*Ln + lane] = (unsigned char)bp;
        }
    }
    __syncthreads();
    if (tid < 64){
        unsigned char cur[Ln];
        #pragma unroll
        for (int q=0;q<Ln;++q) cur[q] = (unsigned char)q;
        #pragma unroll
        for (int k=8;k>=1;--k){
            int ta = 8*tid + k;
            if (ta < Tn){
                const unsigned char* hr = &hist_s[ta*Ln];
                #pragma unroll
                for (int q=0;q<Ln;++q) cur[q] = hr[cur[q]];
            }
        }
        #pragma unroll
        for (int q=0;q<Ln;++q) comp_s[tid*Ln+q] = cur[q];
    }
    __syncthreads();
    if (tid==0){
        int cg = tag_s;
        for (int l=63;l>=0;--l){ ent_s[l]=(unsigned char)cg; cg = comp_s[l*Ln+cg]; }
    }
    __syncthreads();
    if (tid < 64){
        int s = ent_s[tid];
        if (tid==63) path_s[Tn-1] = s;
        #pragma unroll
        for (int k=8;k>=1;--k){
            int ta = 8*tid + k;
            if (ta < Tn){ s = hist_s[ta*Ln+s]; path_s[ta-1] = s; }
        }
    }
    __syncthreads();
    float* lg = logits + (size_t)b*Tn*Ln;
    for (int id2=tid; id2<Tn*Ln; id2+=512){
        int t = id2/Ln; int jj = id2 - t*Ln;
        lg[id2] = (lab2_s[t] && path_s[t]==jj) ? 1.0f : 0.0f;
    }
    if (tid==0) (ws+DIFF_OFF)[b] = score_s - logZ_s;
}

// ---------------- finalize: nll = -mean(score - logZ) ----------------
__global__ __launch_bounds__(64) void fin_kernel(const float* __restrict__ ws,
                                                 float* __restrict__ out0)
{
    float v = (ws+DIFF_OFF)[threadIdx.x];
    #pragma unroll
    for (int off=32; off>=1; off>>=1) v += __shfl_xor(v, off, 64);
    if (threadIdx.x==0) out0[0] = -(v * (1.0f/64.0f));
}

extern "C" void kernel_launch(void* const* d_in, const int* in_sizes, int n_in,
                              void* d_out, int out_size, void* d_ws, size_t ws_size,
                              hipStream_t stream)
{
    (void)in_sizes; (void)n_in; (void)out_size; (void)ws_size;
    const float* hidden = (const float*)d_in[0];
    const float* W      = (const float*)d_in[1];
    const float* bias   = (const float*)d_in[2];
    const float* st     = (const float*)d_in[3];
    const float* et     = (const float*)d_in[4];
    const float* trans  = (const float*)d_in[5];
    const int*   labels = (const int*)d_in[6];
    const int*   amask  = (const int*)d_in[7];

    float* out    = (float*)d_out;
    float* nll    = out;
    float* logits = out + 1;
    float* em     = out + 1 + EM_ELEMS;
    float* ws     = (float*)d_ws;

    emis_kernel<<<dim3(Bn*Tn/64), dim3(256), 0, stream>>>(hidden, W, bias, em);
    fused_kernel<<<dim3(Bn), dim3(512), 0, stream>>>(em, labels, amask, st, et, trans, ws, logits);
    fin_kernel<<<dim3(1), dim3(64), 0, stream>>>(ws, nll);
}